// Round 8
// baseline (286.115 us; speedup 1.0000x reference)
//
#include <hip/hip_runtime.h>
#include <hip/hip_bf16.h>

#define NN 2048
#define BB 8
#define TROW 128928   // sum_{d=1..64} (2047-d)

typedef __attribute__((ext_vector_type(8))) short bf16x8;
typedef __attribute__((ext_vector_type(4))) unsigned u32x4;
typedef __attribute__((ext_vector_type(4))) float f32x4;

// pack 2 fp32 -> 2 bf16 (RNE) in one v_cvt_pk_bf16_f32
__device__ __forceinline__ unsigned pk2(float lo, float hi) {
    float2 t; t.x = lo; t.y = hi;
    __hip_bfloat162 h = __float22bfloat162_rn(t);
    union { __hip_bfloat162 h; unsigned u; } c; c.h = h;
    return c.u;
}

__device__ __forceinline__ float aload(const float* p) {
    return __hip_atomic_load(p, __ATOMIC_RELAXED, __HIP_MEMORY_SCOPE_AGENT);
}

// ---------------- k_stage1: 1536 blocks x 256 thr (6 generations/CU) ----------------
// blocks 0..1023: MFMA row-dots, K-split 4. blk&3 = K-quarter; unit=blk>>2 -> (b, rg).
//   wave w: rows [rg*64 + w*16, +16), 16 MFMA iters over its K-quarter -> Rp[kq].
//   Finer K-split: shorter dependent chains per block + scheduler refill slack.
// blocks 1024..1535: colsum partials. unit -> b, rc(16), jc(4); 128 rows x 512 cols,
//   float2-coalesced loads, wave-uniform s_load weights -> CSp[rc].
// block 0 zeroes psum[64] + counters[4] (stream order makes them visible to k_rest).
__global__ __launch_bounds__(256, 4) void k_stage1(const float* __restrict__ x,
                                                   const float* __restrict__ wl,
                                                   const float* __restrict__ wr,
                                                   float* __restrict__ Rp,
                                                   float* __restrict__ CSp,
                                                   float* __restrict__ psum,
                                                   int* __restrict__ counters) {
    int blk = blockIdx.x;
    int tid = threadIdx.x;
    if (blk == 0) {
        if (tid < 64) psum[tid] = 0.f;
        else if (tid < 68) counters[tid - 64] = 0;
    }
    if (blk < 1024) {
        // ---- MFMA row-dot path, K-quarter ----
        int kq = blk & 3;
        int unit = blk >> 2;
        int b = unit >> 5, rg = unit & 31;
        int w = tid >> 6, lane = tid & 63;
        int q = lane >> 4, m = lane & 15;
        int r0 = rg * 64 + w * 16;
        int nrow = (m == 15) ? 14 : m;

        const float* ap = x + ((size_t)(b * NN + r0 + m)) * NN + kq * 512 + q * 8;
        const float* bp = wl + (size_t)nrow * NN + kq * 512 + q * 8;

        f32x4 acc = {0.f, 0.f, 0.f, 0.f};
#pragma unroll 4
        for (int it = 0; it < 16; it++) {
            const float* a0 = ap + it * 32;
            const float* b0 = bp + it * 32;
            float4 av0 = *(const float4*)(a0);
            float4 av1 = *(const float4*)(a0 + 4);
            float4 bv0 = *(const float4*)(b0);
            float4 bv1 = *(const float4*)(b0 + 4);
            union { bf16x8 v; u32x4 u; } A, Bv;
            A.u[0] = pk2(av0.x, av0.y); A.u[1] = pk2(av0.z, av0.w);
            A.u[2] = pk2(av1.x, av1.y); A.u[3] = pk2(av1.z, av1.w);
            Bv.u[0] = pk2(bv0.x, bv0.y); Bv.u[1] = pk2(bv0.z, bv0.w);
            Bv.u[2] = pk2(bv1.x, bv1.y); Bv.u[3] = pk2(bv1.z, bv1.w);
            acc = __builtin_amdgcn_mfma_f32_16x16x32_bf16(A.v, Bv.v, acc, 0, 0, 0);
        }
        float* rp = Rp + (size_t)kq * (BB * NN * 16) + ((size_t)b * NN + r0) * 16;
#pragma unroll
        for (int reg = 0; reg < 4; reg++)
            rp[(q * 4 + reg) * 16 + m] = acc[reg];
    } else {
        // ---- colsum partial: rows [rc*128,+128) x cols [jc*512,+512), float2 ----
        int u2 = blk - 1024;
        int b = u2 >> 6;
        int rem = u2 & 63;
        int rc = rem >> 2, jc = rem & 3;
        int r0 = rc * 128;
        int c0 = jc * 512 + tid * 2;
        const float* xp = x + ((size_t)b * NN + r0) * NN + c0;

        float acc[15][2];
#pragma unroll
        for (int k = 0; k < 15; k++) { acc[k][0] = 0.f; acc[k][1] = 0.f; }

        for (int rb = 0; rb < 16; rb++) {
            float2 xv[8];
#pragma unroll
            for (int q = 0; q < 8; q++)
                xv[q] = *(const float2*)(xp + (size_t)(rb * 8 + q) * NN);
#pragma unroll
            for (int q = 0; q < 8; q++) {
                int h = r0 + rb * 8 + q;
#pragma unroll
                for (int k = 0; k < 15; k++) {
                    int c = k / 3, dw = k - c * 3;
                    float wk = wr[c * (NN * 3) + h * 3 + dw];  // wave-uniform -> s_load
                    acc[k][0] = fmaf(xv[q].x, wk, acc[k][0]);
                    acc[k][1] = fmaf(xv[q].y, wk, acc[k][1]);
                }
            }
        }
        float* op = CSp + ((size_t)(rc * BB + b) * 16) * NN + c0;
#pragma unroll
        for (int k = 0; k < 15; k++) {
            float2 v; v.x = acc[k][0]; v.y = acc[k][1];
            *(float2*)(op + (size_t)k * NN) = v;
        }
    }
}

// ---------------- k_rest: tail (round-7 proven), 256 blocks x 512 thr, 2 grid barriers ----
__global__ __launch_bounds__(512, 2) void k_rest(const float* __restrict__ x,
                                                 const float* __restrict__ Rp,
                                                 const float* __restrict__ CSp,
                                                 const float* __restrict__ bl,
                                                 const float* __restrict__ br,
                                                 const float* __restrict__ wA, const float* __restrict__ bA,
                                                 const float* __restrict__ wB, const float* __restrict__ bB,
                                                 const float* __restrict__ wT, const float* __restrict__ bT,
                                                 const float* __restrict__ wm, const float* __restrict__ bm,
                                                 float* __restrict__ LEFT, float* __restrict__ RIGHT,
                                                 float* __restrict__ psum,
                                                 int* __restrict__ counters,
                                                 float* __restrict__ outp) {
    __shared__ float T[65][65];
    __shared__ float buf0[10][80], buf1[10][80];
    __shared__ float W[3][10][10][3];
    __shared__ float Bs[3][10];
    __shared__ float Wm[2][10], Bm[2];
    __shared__ float psl[64];
    __shared__ float lfs[132], rts[68];

    const int tid = threadIdx.x;
    const int b   = blockIdx.x >> 5;
    const int rg  = blockIdx.x & 31;
    const int i0  = rg << 6;
    const int w   = tid >> 6;
    const int lane = tid & 63;

    // ---- conv weights + T tile (x L3-hot from k_stage1) ----
    for (int idx = tid; idx < 900; idx += 512) {
        int set = idx / 300, rem = idx - set * 300;
        int o = rem / 30, rem2 = rem - o * 30, c = rem2 / 3, kk = rem2 - c * 3;
        float u;
        if (set == 0) u = wA[o * 30 + c * 3 + kk];
        else if (set == 1) u = wB[o * 30 + c * 3 + kk];
        else u = wT[c * 30 + o * 3 + (2 - kk)];   // wTc[o,c,k] = wT[c,o,2-k]
        W[set][o][c][kk] = u;
    }
    if (tid < 30) {
        float v = (tid < 10) ? bA[tid] : (tid < 20) ? bB[tid - 10] : bT[tid - 20];
        Bs[tid / 10][tid % 10] = v;
    }
    if (tid < 20) Wm[tid / 10][tid % 10] = wm[tid];
    if (tid < 2) Bm[tid] = bm[tid];

    for (int idx = tid; idx < 65 * 64; idx += 512) {
        int r = idx >> 6, dm1 = idx & 63;
        int row = i0 + r;
        int col = row + dm1 + 1;
        float v = 0.f;
        if (row < NN && col < NN) v = __expf(x[((size_t)b * NN + row) * NN + col]);
        T[r][dm1] = v;
    }

    // ---- combine: fold Rp[4] + CSp[16] (plain loads; kernel boundary = visibility) ----
    for (int idx = tid; idx < 760; idx += 512) {
        int ch = idx / 76, p = idx - ch * 76;
        int g = i0 - 6 + p;
        float v = 0.f;
        if (g >= 0 && g < NN) {
            if (ch < 5) {
                v = bl[ch];
#pragma unroll
                for (int dh = 0; dh < 3; dh++) {
                    int r = g - 1 + dh;
                    if (r >= 0 && r < NN) {
                        const float* p0 = Rp + ((size_t)b * NN + r) * 16 + ch * 3 + dh;
                        v += p0[0] + p0[(size_t)BB * NN * 16]
                           + p0[2 * (size_t)BB * NN * 16] + p0[3 * (size_t)BB * NN * 16];
                    }
                }
            } else {
                int c = ch - 5;
                v = br[c];
#pragma unroll
                for (int dw = 0; dw < 3; dw++) {
                    int j = g - 1 + dw;
                    if (j >= 0 && j < NN) {
                        const float* base = CSp + ((size_t)b * 16 + c * 3 + dw) * NN + j;
                        float t[16];
#pragma unroll
                        for (int rc = 0; rc < 16; rc++)
                            t[rc] = base[(size_t)rc * (8 * 16 * NN)];
                        float s = 0.f;
#pragma unroll
                        for (int rc = 0; rc < 16; rc++) s += t[rc];
                        v += s;
                    }
                }
            }
        }
        buf0[ch][p] = v;
    }
    __syncthreads();

    // ---- 6 conv layers ----
    float(*in)[80] = buf0;
    float(*out)[80] = buf1;
    for (int layer = 0; layer < 6; layer++) {
        int set = (layer == 0) ? 0 : (layer < 3 ? 1 : 2);
        int lo = layer + 1;  // valid p range [lo, 76-lo)
        for (int idx = tid; idx < 760; idx += 512) {
            int o = idx / 76, p = idx - o * 76;
            if (p >= lo && p < 76 - lo) {
                float s = Bs[set][o];
#pragma unroll
                for (int c = 0; c < 10; c++) {
                    const float* ip = &in[c][p];
                    s = fmaf(ip[-1], W[set][o][c][0], s);
                    s = fmaf(ip[0], W[set][o][c][1], s);
                    s = fmaf(ip[1], W[set][o][c][2], s);
                }
                s = s > 0.f ? s : 0.f;
                int g = i0 - 6 + p;
                if (g < 0 || g >= NN) s = 0.f;  // reproduce zero padding at global edges
                out[o][p] = s;
            }
        }
        __syncthreads();
        float(*tmp)[80] = in; in = out; out = tmp;
    }

    // ---- 1x1 head + sigmoid; agent-scope stores for cross-XCD visibility ----
    if (tid < 128) {
        int o = tid >> 6, pp = tid & 63;
        int p = 6 + pp;
        float s = Bm[o];
#pragma unroll
        for (int c = 0; c < 10; c++) s = fmaf(in[c][p], Wm[o][c], s);
        float sig = 1.f / (1.f + __expf(-s));
        float* dst = (o ? RIGHT : LEFT) + b * NN + i0 + pp;
        __hip_atomic_store(dst, sig, __ATOMIC_RELAXED, __HIP_MEMORY_SCOPE_AGENT);
    }
    __syncthreads();

    // ---- grid barrier 0: LEFT/RIGHT complete ----
    if (tid == 0) {
        __threadfence();
        atomicAdd(&counters[0], 1);
        while (__hip_atomic_load(&counters[0], __ATOMIC_ACQUIRE, __HIP_MEMORY_SCOPE_AGENT) < 256) {
            __builtin_amdgcn_s_sleep(2);
        }
    }
    __syncthreads();

    // ---- stage LEFT/RIGHT slices ----
    if (tid < 195) {
        if (tid < 129) {
            int g = i0 + 1 + tid; if (g > NN - 1) g = NN - 1;
            lfs[tid] = aload(LEFT + b * NN + g);
        } else {
            int p2 = tid - 129;
            int g = i0 + p2; if (g > NN - 1) g = NN - 1;
            rts[p2] = aload(RIGHT + b * NN + g);
        }
    }
    __syncthreads();

    // ---- p values + psum (8 waves x 8 diagonals) ----
    int i = i0 + lane;
    float pv[8];
#pragma unroll
    for (int s = 0; s < 8; s++) {
        int dm1 = w * 8 + s;
        int d = dm1 + 1;
        int L = (NN - 1) - d;
        float p = 0.f;
        if (i < L) {
            float mi = T[lane + 1][dm1] * rts[lane + 1] + T[lane][dm1] * lfs[dm1 + lane];
            float mo = rts[lane] + lfs[dm1 + lane + 1];
            p = __logf(mi / mo);
        }
        pv[s] = p;
        float s64 = p;
        for (int off = 32; off; off >>= 1) s64 += __shfl_down(s64, off);
        if (lane == 0) psl[dm1] = s64;
    }
    __syncthreads();
    if (tid < 64) atomicAdd(&psum[tid], psl[tid]);
    __syncthreads();

    // ---- grid barrier 1: psum complete ----
    if (tid == 0) {
        __threadfence();
        atomicAdd(&counters[1], 1);
        while (__hip_atomic_load(&counters[1], __ATOMIC_ACQUIRE, __HIP_MEMORY_SCOPE_AGENT) < 256) {
            __builtin_amdgcn_s_sleep(2);
        }
    }
    __syncthreads();
    if (tid < 64)
        psl[tid] = aload(&psum[tid]);
    __syncthreads();

    // ---- output ----
#pragma unroll
    for (int s = 0; s < 8; s++) {
        int dm1 = w * 8 + s;
        int d = dm1 + 1;
        int L = (NN - 1) - d;
        if (i < L) {
            float mean = psl[dm1] / (float)(8 * L);
            size_t off0 = (size_t)dm1 * (NN - 1) - (size_t)dm1 * (dm1 + 1) / 2;
            outp[(size_t)b * TROW + off0 + i] = pv[s] - mean;
        }
    }
}

extern "C" void kernel_launch(void* const* d_in, const int* in_sizes, int n_in,
                              void* d_out, int out_size, void* d_ws, size_t ws_size,
                              hipStream_t stream) {
    const float* x = (const float*)d_in[0];
    const float* wl = (const float*)d_in[1];
    const float* bl = (const float*)d_in[2];
    const float* wr = (const float*)d_in[3];
    const float* br = (const float*)d_in[4];
    const float* wA = (const float*)d_in[5];
    const float* bA = (const float*)d_in[6];
    const float* wB = (const float*)d_in[7];
    const float* bB = (const float*)d_in[8];
    const float* wT = (const float*)d_in[9];
    const float* bT = (const float*)d_in[10];
    const float* wm = (const float*)d_in[11];
    const float* bm = (const float*)d_in[12];

    float* ws = (float*)d_ws;
    float* Rp    = ws;                    // 4*8*2048*16  = 1048576 f
    float* CSp   = ws + 1048576;          // 16*8*16*2048 = 4194304 f
    float* LEFT  = ws + 5242880;          // 16384 f
    float* RIGHT = ws + 5259264;          // 16384 f
    float* psum  = ws + 5275648;          // 64 f   (zeroed by k_stage1 blk0)
    int*   counters = (int*)(ws + 5275712);  // 4 ints (zeroed by k_stage1 blk0)

    k_stage1<<<1536, 256, 0, stream>>>(x, wl, wr, Rp, CSp, psum, counters);
    k_rest<<<256, 512, 0, stream>>>(x, Rp, CSp, bl, br, wA, bA, wB, bB, wT, bT, wm, bm,
                                    LEFT, RIGHT, psum, counters, (float*)d_out);
}

// Round 9
// 281.157 us; speedup vs baseline: 1.0176x; 1.0176x over previous
//
#include <hip/hip_runtime.h>
#include <hip/hip_bf16.h>

#define NN 2048
#define BB 8
#define TROW 128928   // sum_{d=1..64} (2047-d)

typedef __attribute__((ext_vector_type(8))) short bf16x8;
typedef __attribute__((ext_vector_type(4))) unsigned u32x4;
typedef __attribute__((ext_vector_type(4))) float f32x4;

// pack 2 fp32 -> 2 bf16 (RNE) in one v_cvt_pk_bf16_f32
__device__ __forceinline__ unsigned pk2(float lo, float hi) {
    float2 t; t.x = lo; t.y = hi;
    __hip_bfloat162 h = __float22bfloat162_rn(t);
    union { __hip_bfloat162 h; unsigned u; } c; c.h = h;
    return c.u;
}

__device__ __forceinline__ float aload(const float* p) {
    return __hip_atomic_load(p, __ATOMIC_RELAXED, __HIP_MEMORY_SCOPE_AGENT);
}

// ---------------- k_stage1: round-7 exact (best measured), 1024 blocks x 256 thr ----------------
// blocks 0..511: MFMA row-dots, K-split 2. blk&1 = K-half; unit=blk>>1 -> (b, rg).
// blocks 512..1023: colsum partials, 128 rows x 512 cols, float2, s_load weights -> CSp[16].
// block 0 zeroes psum[64] + counters[4].
__global__ __launch_bounds__(256, 4) void k_stage1(const float* __restrict__ x,
                                                   const float* __restrict__ wl,
                                                   const float* __restrict__ wr,
                                                   float* __restrict__ Rp,
                                                   float* __restrict__ CSp,
                                                   float* __restrict__ psum,
                                                   int* __restrict__ counters) {
    int blk = blockIdx.x;
    int tid = threadIdx.x;
    if (blk == 0) {
        if (tid < 64) psum[tid] = 0.f;
        else if (tid < 68) counters[tid - 64] = 0;
    }
    if (blk < 512) {
        // ---- MFMA row-dot path, K-half ----
        int kh = blk & 1;
        int unit = blk >> 1;
        int b = unit >> 5, rg = unit & 31;
        int w = tid >> 6, lane = tid & 63;
        int q = lane >> 4, m = lane & 15;
        int r0 = rg * 64 + w * 16;
        int nrow = (m == 15) ? 14 : m;

        const float* ap = x + ((size_t)(b * NN + r0 + m)) * NN + kh * 1024 + q * 8;
        const float* bp = wl + (size_t)nrow * NN + kh * 1024 + q * 8;

        f32x4 acc = {0.f, 0.f, 0.f, 0.f};
#pragma unroll 4
        for (int it = 0; it < 32; it++) {
            const float* a0 = ap + it * 32;
            const float* b0 = bp + it * 32;
            float4 av0 = *(const float4*)(a0);
            float4 av1 = *(const float4*)(a0 + 4);
            float4 bv0 = *(const float4*)(b0);
            float4 bv1 = *(const float4*)(b0 + 4);
            union { bf16x8 v; u32x4 u; } A, Bv;
            A.u[0] = pk2(av0.x, av0.y); A.u[1] = pk2(av0.z, av0.w);
            A.u[2] = pk2(av1.x, av1.y); A.u[3] = pk2(av1.z, av1.w);
            Bv.u[0] = pk2(bv0.x, bv0.y); Bv.u[1] = pk2(bv0.z, bv0.w);
            Bv.u[2] = pk2(bv1.x, bv1.y); Bv.u[3] = pk2(bv1.z, bv1.w);
            acc = __builtin_amdgcn_mfma_f32_16x16x32_bf16(A.v, Bv.v, acc, 0, 0, 0);
        }
        float* rp = Rp + (size_t)kh * (BB * NN * 16) + ((size_t)b * NN + r0) * 16;
#pragma unroll
        for (int reg = 0; reg < 4; reg++)
            rp[(q * 4 + reg) * 16 + m] = acc[reg];
    } else {
        // ---- colsum partial: rows [rc*128,+128) x cols [jc*512,+512), float2 ----
        int u2 = blk - 512;
        int b = u2 >> 6;
        int rem = u2 & 63;
        int rc = rem >> 2, jc = rem & 3;
        int r0 = rc * 128;
        int c0 = jc * 512 + tid * 2;
        const float* xp = x + ((size_t)b * NN + r0) * NN + c0;

        float acc[15][2];
#pragma unroll
        for (int k = 0; k < 15; k++) { acc[k][0] = 0.f; acc[k][1] = 0.f; }

        for (int rb = 0; rb < 16; rb++) {
            float2 xv[8];
#pragma unroll
            for (int q = 0; q < 8; q++)
                xv[q] = *(const float2*)(xp + (size_t)(rb * 8 + q) * NN);
#pragma unroll
            for (int q = 0; q < 8; q++) {
                int h = r0 + rb * 8 + q;
#pragma unroll
                for (int k = 0; k < 15; k++) {
                    int c = k / 3, dw = k - c * 3;
                    float wk = wr[c * (NN * 3) + h * 3 + dw];  // wave-uniform -> s_load
                    acc[k][0] = fmaf(xv[q].x, wk, acc[k][0]);
                    acc[k][1] = fmaf(xv[q].y, wk, acc[k][1]);
                }
            }
        }
        float* op = CSp + ((size_t)(rc * BB + b) * 16) * NN + c0;
#pragma unroll
        for (int k = 0; k < 15; k++) {
            float2 v; v.x = acc[k][0]; v.y = acc[k][1];
            *(float2*)(op + (size_t)k * NN) = v;
        }
    }
}

// ---------------- k_rest: tail at 1024 thr (16 waves/CU), 256 blocks, 2 grid barriers ----------
__global__ __launch_bounds__(1024, 4) void k_rest(const float* __restrict__ x,
                                                  const float* __restrict__ Rp,
                                                  const float* __restrict__ CSp,
                                                  const float* __restrict__ bl,
                                                  const float* __restrict__ br,
                                                  const float* __restrict__ wA, const float* __restrict__ bA,
                                                  const float* __restrict__ wB, const float* __restrict__ bB,
                                                  const float* __restrict__ wT, const float* __restrict__ bT,
                                                  const float* __restrict__ wm, const float* __restrict__ bm,
                                                  float* __restrict__ LEFT, float* __restrict__ RIGHT,
                                                  float* __restrict__ psum,
                                                  int* __restrict__ counters,
                                                  float* __restrict__ outp) {
    __shared__ float T[65][65];
    __shared__ float buf0[10][80], buf1[10][80];
    __shared__ float W[3][10][10][3];
    __shared__ float Bs[3][10];
    __shared__ float Wm[2][10], Bm[2];
    __shared__ float psl[64];
    __shared__ float lfs[132], rts[68];

    const int tid = threadIdx.x;
    const int b   = blockIdx.x >> 5;
    const int rg  = blockIdx.x & 31;
    const int i0  = rg << 6;
    const int w   = tid >> 6;            // 0..15
    const int lane = tid & 63;

    // ---- conv weights + T tile (x L3-hot from k_stage1) ----
    for (int idx = tid; idx < 900; idx += 1024) {
        int set = idx / 300, rem = idx - set * 300;
        int o = rem / 30, rem2 = rem - o * 30, c = rem2 / 3, kk = rem2 - c * 3;
        float u;
        if (set == 0) u = wA[o * 30 + c * 3 + kk];
        else if (set == 1) u = wB[o * 30 + c * 3 + kk];
        else u = wT[c * 30 + o * 3 + (2 - kk)];   // wTc[o,c,k] = wT[c,o,2-k]
        W[set][o][c][kk] = u;
    }
    if (tid < 30) {
        float v = (tid < 10) ? bA[tid] : (tid < 20) ? bB[tid - 10] : bT[tid - 20];
        Bs[tid / 10][tid % 10] = v;
    }
    if (tid < 20) Wm[tid / 10][tid % 10] = wm[tid];
    if (tid < 2) Bm[tid] = bm[tid];

    for (int idx = tid; idx < 65 * 64; idx += 1024) {
        int r = idx >> 6, dm1 = idx & 63;
        int row = i0 + r;
        int col = row + dm1 + 1;
        float v = 0.f;
        if (row < NN && col < NN) v = __expf(x[((size_t)b * NN + row) * NN + col]);
        T[r][dm1] = v;
    }

    // ---- combine: fold Rp[2] + CSp[16] (plain loads; kernel boundary = visibility) ----
    for (int idx = tid; idx < 760; idx += 1024) {
        int ch = idx / 76, p = idx - ch * 76;
        int g = i0 - 6 + p;
        float v = 0.f;
        if (g >= 0 && g < NN) {
            if (ch < 5) {
                v = bl[ch];
#pragma unroll
                for (int dh = 0; dh < 3; dh++) {
                    int r = g - 1 + dh;
                    if (r >= 0 && r < NN) {
                        const float* p0 = Rp + ((size_t)b * NN + r) * 16 + ch * 3 + dh;
                        v += p0[0] + p0[(size_t)BB * NN * 16];
                    }
                }
            } else {
                int c = ch - 5;
                v = br[c];
#pragma unroll
                for (int dw = 0; dw < 3; dw++) {
                    int j = g - 1 + dw;
                    if (j >= 0 && j < NN) {
                        const float* base = CSp + ((size_t)b * 16 + c * 3 + dw) * NN + j;
                        float t[16];
#pragma unroll
                        for (int rc = 0; rc < 16; rc++)
                            t[rc] = base[(size_t)rc * (8 * 16 * NN)];
                        float s = 0.f;
#pragma unroll
                        for (int rc = 0; rc < 16; rc++) s += t[rc];
                        v += s;
                    }
                }
            }
        }
        buf0[ch][p] = v;
    }
    __syncthreads();

    // ---- 6 conv layers ----
    float(*in)[80] = buf0;
    float(*out)[80] = buf1;
    for (int layer = 0; layer < 6; layer++) {
        int set = (layer == 0) ? 0 : (layer < 3 ? 1 : 2);
        int lo = layer + 1;  // valid p range [lo, 76-lo)
        for (int idx = tid; idx < 760; idx += 1024) {
            int o = idx / 76, p = idx - o * 76;
            if (p >= lo && p < 76 - lo) {
                float s = Bs[set][o];
#pragma unroll
                for (int c = 0; c < 10; c++) {
                    const float* ip = &in[c][p];
                    s = fmaf(ip[-1], W[set][o][c][0], s);
                    s = fmaf(ip[0], W[set][o][c][1], s);
                    s = fmaf(ip[1], W[set][o][c][2], s);
                }
                s = s > 0.f ? s : 0.f;
                int g = i0 - 6 + p;
                if (g < 0 || g >= NN) s = 0.f;  // reproduce zero padding at global edges
                out[o][p] = s;
            }
        }
        __syncthreads();
        float(*tmp)[80] = in; in = out; out = tmp;
    }

    // ---- 1x1 head + sigmoid; agent-scope stores for cross-XCD visibility ----
    if (tid < 128) {
        int o = tid >> 6, pp = tid & 63;
        int p = 6 + pp;
        float s = Bm[o];
#pragma unroll
        for (int c = 0; c < 10; c++) s = fmaf(in[c][p], Wm[o][c], s);
        float sig = 1.f / (1.f + __expf(-s));
        float* dst = (o ? RIGHT : LEFT) + b * NN + i0 + pp;
        __hip_atomic_store(dst, sig, __ATOMIC_RELAXED, __HIP_MEMORY_SCOPE_AGENT);
    }
    __syncthreads();

    // ---- grid barrier 0: LEFT/RIGHT complete ----
    if (tid == 0) {
        __threadfence();
        atomicAdd(&counters[0], 1);
        while (__hip_atomic_load(&counters[0], __ATOMIC_ACQUIRE, __HIP_MEMORY_SCOPE_AGENT) < 256) {
            __builtin_amdgcn_s_sleep(2);
        }
    }
    __syncthreads();

    // ---- stage LEFT/RIGHT slices ----
    if (tid < 195) {
        if (tid < 129) {
            int g = i0 + 1 + tid; if (g > NN - 1) g = NN - 1;
            lfs[tid] = aload(LEFT + b * NN + g);
        } else {
            int p2 = tid - 129;
            int g = i0 + p2; if (g > NN - 1) g = NN - 1;
            rts[p2] = aload(RIGHT + b * NN + g);
        }
    }
    __syncthreads();

    // ---- p values + psum (16 waves x 4 diagonals) ----
    int i = i0 + lane;
    float pv[4];
#pragma unroll
    for (int s = 0; s < 4; s++) {
        int dm1 = w * 4 + s;
        int d = dm1 + 1;
        int L = (NN - 1) - d;
        float p = 0.f;
        if (i < L) {
            float mi = T[lane + 1][dm1] * rts[lane + 1] + T[lane][dm1] * lfs[dm1 + lane];
            float mo = rts[lane] + lfs[dm1 + lane + 1];
            p = __logf(mi / mo);
        }
        pv[s] = p;
        float s64 = p;
        for (int off = 32; off; off >>= 1) s64 += __shfl_down(s64, off);
        if (lane == 0) psl[dm1] = s64;
    }
    __syncthreads();
    if (tid < 64) atomicAdd(&psum[tid], psl[tid]);
    __syncthreads();

    // ---- grid barrier 1: psum complete ----
    if (tid == 0) {
        __threadfence();
        atomicAdd(&counters[1], 1);
        while (__hip_atomic_load(&counters[1], __ATOMIC_ACQUIRE, __HIP_MEMORY_SCOPE_AGENT) < 256) {
            __builtin_amdgcn_s_sleep(2);
        }
    }
    __syncthreads();
    if (tid < 64)
        psl[tid] = aload(&psum[tid]);
    __syncthreads();

    // ---- output ----
#pragma unroll
    for (int s = 0; s < 4; s++) {
        int dm1 = w * 4 + s;
        int d = dm1 + 1;
        int L = (NN - 1) - d;
        if (i < L) {
            float mean = psl[dm1] / (float)(8 * L);
            size_t off0 = (size_t)dm1 * (NN - 1) - (size_t)dm1 * (dm1 + 1) / 2;
            outp[(size_t)b * TROW + off0 + i] = pv[s] - mean;
        }
    }
}

extern "C" void kernel_launch(void* const* d_in, const int* in_sizes, int n_in,
                              void* d_out, int out_size, void* d_ws, size_t ws_size,
                              hipStream_t stream) {
    const float* x = (const float*)d_in[0];
    const float* wl = (const float*)d_in[1];
    const float* bl = (const float*)d_in[2];
    const float* wr = (const float*)d_in[3];
    const float* br = (const float*)d_in[4];
    const float* wA = (const float*)d_in[5];
    const float* bA = (const float*)d_in[6];
    const float* wB = (const float*)d_in[7];
    const float* bB = (const float*)d_in[8];
    const float* wT = (const float*)d_in[9];
    const float* bT = (const float*)d_in[10];
    const float* wm = (const float*)d_in[11];
    const float* bm = (const float*)d_in[12];

    float* ws = (float*)d_ws;
    float* Rp    = ws;                    // 2*8*2048*16  = 524288 f
    float* CSp   = ws + 524288;           // 16*8*16*2048 = 4194304 f
    float* LEFT  = ws + 4718592;          // 16384 f
    float* RIGHT = ws + 4734976;          // 16384 f
    float* psum  = ws + 4751360;          // 64 f   (zeroed by k_stage1 blk0)
    int*   counters = (int*)(ws + 4751424);  // 4 ints (zeroed by k_stage1 blk0)

    k_stage1<<<1024, 256, 0, stream>>>(x, wl, wr, Rp, CSp, psum, counters);
    k_rest<<<256, 1024, 0, stream>>>(x, Rp, CSp, bl, br, wA, bA, wB, bB, wT, bT, wm, bm,
                                     LEFT, RIGHT, psum, counters, (float*)d_out);
}